// Round 13
// baseline (536.433 us; speedup 1.0000x reference)
//
#include <hip/hip_runtime.h>
#include <hip/hip_bf16.h>

typedef __hip_bfloat16 bf16;
typedef __attribute__((ext_vector_type(8))) short bf16x8;
typedef __attribute__((ext_vector_type(4))) float f32x4;

#define HEADS 16
#define HDIM  64
#define DIM   1024
#define SEQ   2048
#define BATCH 4
#define BS    (BATCH * SEQ)   // 8192
#define CS    0.1803368801111f  // (1/8) * log2(e): folded into Q at proj time
#define QBLK  128

#define EXP2F(x) __builtin_amdgcn_exp2f(x)
#define LOG2F(x) __builtin_amdgcn_logf(x)
#define MFMA16(a, b, c) __builtin_amdgcn_mfma_f32_16x16x32_bf16(a, b, c, 0, 0, 0)

__device__ __forceinline__ void gload_lds16(const void* g, void* l) {
    __builtin_amdgcn_global_load_lds(
        (const __attribute__((address_space(1))) void*)g,
        (__attribute__((address_space(3))) void*)l, 16, 0, 0);
}

__device__ __forceinline__ void cvt8(const float* __restrict__ src, bf16* __restrict__ dst,
                                     size_t i)
{
    float4 f0 = *(const float4*)&src[i];
    float4 f1 = *(const float4*)&src[i + 4];
    union { bf16 h[8]; uint4 u; } pk;
    pk.h[0] = __float2bfloat16(f0.x); pk.h[1] = __float2bfloat16(f0.y);
    pk.h[2] = __float2bfloat16(f0.z); pk.h[3] = __float2bfloat16(f0.w);
    pk.h[4] = __float2bfloat16(f1.x); pk.h[5] = __float2bfloat16(f1.y);
    pk.h[6] = __float2bfloat16(f1.z); pk.h[7] = __float2bfloat16(f1.w);
    *(uint4*)&dst[i] = pk.u;
}

// ---------------------------------------------------------------------------
// Kernel 0a: fp32 -> bf16 for Q,K,V,Wq,Wk,Wv.
// ---------------------------------------------------------------------------
__global__ __launch_bounds__(256) void cvt_kernel(
    const float* __restrict__ Q, const float* __restrict__ K, const float* __restrict__ V,
    const float* __restrict__ Wq, const float* __restrict__ Wk, const float* __restrict__ Wv,
    bf16* __restrict__ xq, bf16* __restrict__ xk, bf16* __restrict__ xv,
    bf16* __restrict__ wq, bf16* __restrict__ wk, bf16* __restrict__ wv)
{
    const int seg = blockIdx.y;
    const float* src; bf16* dst; size_t n;
    switch (seg) {
        case 0: src = Q;  dst = xq; n = (size_t)BS * DIM;   break;
        case 1: src = K;  dst = xk; n = (size_t)BS * DIM;   break;
        case 2: src = V;  dst = xv; n = (size_t)BS * DIM;   break;
        case 3: src = Wq; dst = wq; n = (size_t)DIM * DIM;  break;
        case 4: src = Wk; dst = wk; n = (size_t)DIM * DIM;  break;
        default: src = Wv; dst = wv; n = (size_t)DIM * DIM; break;
    }
    size_t i = ((size_t)blockIdx.x * 256 + threadIdx.x) * 8;
    if (i >= n) return;
    cvt8(src, dst, i);
}

// Kernel 0b: Wo fp32 -> bf16, AFTER attn into the then-dead qws region.
__global__ __launch_bounds__(256) void cvt_wo_kernel(
    const float* __restrict__ Wo, bf16* __restrict__ wo)
{
    size_t i = ((size_t)blockIdx.x * 256 + threadIdx.x) * 8;
    cvt8(Wo, wo, i);
}

// ---------------------------------------------------------------------------
// MFMA GEMM core (fragment-linear LDS, round-2 comment).  SWAP flips the
// C-layout so the register dim indexes B-rows (packed row-major stores).
// ---------------------------------------------------------------------------
template <bool SWAP>
__device__ __forceinline__ void mfma_core_1024(
    const bf16* __restrict__ A, const bf16* __restrict__ B,
    int m0, int n0, bf16* sA, f32x4 acc[4][4])
{
    const int tid = threadIdx.x, lane = tid & 63, wave = tid >> 6;
    const int l15 = lane & 15, lg = lane >> 4;
    const int wr = wave >> 1, wc = wave & 1;
    bf16* sB = sA + 16 * 512;

    const bf16* gsrc = (wave < 2) ? A : B;
    const int   gm0  = (wave < 2) ? m0 : n0;
    bf16*       sdst = (wave < 2) ? sA : sB;
    const int   wv2  = wave & 1;

#define STAGE(k0_) { \
    _Pragma("unroll") for (int u = 0; u < 8; ++u) { \
        const int c = wv2 * 8 + u; \
        const int mg = c >> 1, s = c & 1; \
        gload_lds16(gsrc + (size_t)(gm0 + mg * 16 + l15) * DIM + (k0_) + s * 32 + lg * 8, \
                    sdst + c * 512); \
    } }

    STAGE(0);
#pragma unroll 1
    for (int t = 0; t < DIM / 64; ++t) {
        __syncthreads();
#pragma unroll
        for (int s = 0; s < 2; ++s) {
            bf16x8 af[4], bfr[4];
#pragma unroll
            for (int i = 0; i < 4; ++i)
                af[i] = *(const bf16x8*)(sA + ((wr * 4 + i) * 2 + s) * 512 + lane * 8);
#pragma unroll
            for (int j = 0; j < 4; ++j)
                bfr[j] = *(const bf16x8*)(sB + ((wc * 4 + j) * 2 + s) * 512 + lane * 8);
#pragma unroll
            for (int i = 0; i < 4; ++i)
#pragma unroll
                for (int j = 0; j < 4; ++j) {
                    if (SWAP) acc[i][j] = MFMA16(bfr[j], af[i], acc[i][j]);
                    else      acc[i][j] = MFMA16(af[i], bfr[j], acc[i][j]);
                }
        }
        __syncthreads();
        if (t < DIM / 64 - 1) STAGE((t + 1) * 64);
    }
#undef STAGE
}

// ---------------------------------------------------------------------------
// Kernel 1: QKV projections.  Q out is PRE-SCALED by CS.
// ---------------------------------------------------------------------------
__global__ __launch_bounds__(256) void proj_mfma_kernel(
    const bf16* __restrict__ Xq, const bf16* __restrict__ Xk, const bf16* __restrict__ Xv,
    const bf16* __restrict__ Wq, const bf16* __restrict__ Wk, const bf16* __restrict__ Wv,
    bf16* __restrict__ qo, bf16* __restrict__ ko, bf16* __restrict__ vo)
{
    __shared__ alignas(16) bf16 smem[16384];   // 32 KB
    const int z = blockIdx.z;
    const bf16* X = z == 0 ? Xq : z == 1 ? Xk : Xv;
    const bf16* W = z == 0 ? Wq : z == 1 ? Wk : Wv;
    const int m0 = blockIdx.y * 128, n0 = blockIdx.x * 128;

    const int tid = threadIdx.x, lane = tid & 63, wave = tid >> 6;
    const int l15 = lane & 15, lg = lane >> 4, wr = wave >> 1, wc = wave & 1;
    const int h = blockIdx.x * 2 + wc;     // 128-wide n-tile spans 2 heads

    f32x4 acc[4][4] = {};
    if (z != 2) {
        mfma_core_1024<true>(X, W, m0, n0, smem, acc);
        const float osc = (z == 0) ? CS : 1.0f;   // fold softmax scale into Q
        bf16* O = z == 0 ? qo : ko;
#pragma unroll
        for (int i = 0; i < 4; ++i) {
            int m = m0 + wr * 64 + i * 16 + l15;
            int bb = m >> 11, ss = m & (SEQ - 1);
            size_t base = ((size_t)(bb * HEADS + h) * SEQ + ss) * HDIM;
#pragma unroll
            for (int j = 0; j < 4; ++j) {
                union { bf16 h4[4]; uint2 u; } pk;
#pragma unroll
                for (int r = 0; r < 4; ++r) pk.h4[r] = __float2bfloat16(acc[i][j][r] * osc);
                *(uint2*)&O[base + j * 16 + lg * 4] = pk.u;
            }
        }
    } else {
        mfma_core_1024<false>(X, W, m0, n0, smem, acc);
#pragma unroll
        for (int i = 0; i < 4; ++i) {
            int s0 = m0 + wr * 64 + i * 16 + lg * 4;
            int bb = s0 >> 11, ss = s0 & (SEQ - 1);
#pragma unroll
            for (int j = 0; j < 4; ++j) {
                int d = j * 16 + l15;
                union { bf16 h4[4]; uint2 u; } pk;
#pragma unroll
                for (int r = 0; r < 4; ++r) pk.h4[r] = __float2bfloat16(acc[i][j][r]);
                *(uint2*)&vo[((size_t)(bb * HEADS + h) * HDIM + d) * SEQ + ss] = pk.u;
            }
        }
    }
}

// ---------------------------------------------------------------------------
// Kernel 2: causal attention.  QBLK=128 with 4 waves / 256 threads: each
// wave owns TWO 16-row q-groups (A: 32w..32w+15, B: +16).  K-fragment LDS
// reads are shared by both groups (16 MFMAs per 8 reads); K/V staged once
// per 128 q-rows -> per-(b,h) read demand and barrier count both halve vs
// QBLK=64.  Sync width unchanged (the r7 failure isolated to 512-thr sync).
// No-max exp2 softmax (r12), NT weight stores (r10), PV-swap packed O (r9).
// ---------------------------------------------------------------------------
__global__ __launch_bounds__(256) void attn_kernel(
    const bf16* __restrict__ qws, const bf16* __restrict__ kws, const bf16* __restrict__ vtws,
    float* __restrict__ weights, bf16* __restrict__ attn_out)
{
    __shared__ alignas(16) bf16 Ks[4096];
    __shared__ alignas(16) bf16 Vs[4096];
    __shared__ alignas(16) bf16 Ps[8192];   // 4 waves x 4 chunks x 512

    const int tid  = threadIdx.x;
    const int lane = tid & 63;
    const int wave = tid >> 6;
    const int l15  = lane & 15;
    const int lg   = lane >> 4;
    const int qt = (int)gridDim.x - 1 - (int)blockIdx.x;  // heavy blocks first
    const int h  = blockIdx.y, b = blockIdx.z;
    const int bh = b * HEADS + h;
    const int q0 = qt * QBLK;
    const int qlA = 32 * wave + l15;       // local q row, group A (B = +16)
    const int nkt = 2 * qt + 2;            // 64-wide k-tiles to process

    const bf16* qbase = qws + (size_t)bh * SEQ * HDIM;
    const bf16* kbase = kws + (size_t)bh * SEQ * HDIM;
    const bf16* vbase = vtws + (size_t)bh * HDIM * SEQ;

    bf16x8 qa0A, qa1A, qa0B, qa1B;
    {
        const bf16* qp = qbase + (size_t)(q0 + qlA) * HDIM + lg * 8;
        qa0A = *(const bf16x8*)qp;
        qa1A = *(const bf16x8*)(qp + 32);
        qa0B = *(const bf16x8*)(qp + 16 * HDIM);
        qa1B = *(const bf16x8*)(qp + 16 * HDIM + 32);
    }

#define LOADK(kt_, r0, r1) { \
    const bf16* rp = kbase + (size_t)((kt_) * 64 + 16 * wave + l15) * HDIM + lg * 8; \
    r0 = *(const uint4*)rp; r1 = *(const uint4*)(rp + 32); }
#define STOREK(r0, r1) { \
    *(uint4*)&Ks[((wave * 2 + 0) * 64 + lane) * 8] = r0; \
    *(uint4*)&Ks[((wave * 2 + 1) * 64 + lane) * 8] = r1; }
#define LOADV(kt_, r0, r1) { \
    const bf16* rp = vbase + (size_t)(16 * wave + l15) * SEQ + (kt_) * 64 + lg * 8; \
    r0 = *(const uint4*)rp; r1 = *(const uint4*)(rp + 32); }
#define STOREV(r0, r1) { \
    *(uint4*)&Vs[((wave * 2 + 0) * 64 + lane) * 8] = r0; \
    *(uint4*)&Vs[((wave * 2 + 1) * 64 + lane) * 8] = r1; }
// swapped QK^T, both q-groups sharing the K-fragment reads:
#define QKT2(accA_, accB_) { \
    _Pragma("unroll") \
    for (int ct = 0; ct < 4; ++ct) { \
        bf16x8 b0 = *(const bf16x8*)&Ks[((ct * 2 + 0) * 64 + lane) * 8]; \
        bf16x8 b1 = *(const bf16x8*)&Ks[((ct * 2 + 1) * 64 + lane) * 8]; \
        accA_[ct] = MFMA16(b0, qa0A, accA_[ct]); \
        accA_[ct] = MFMA16(b1, qa1A, accA_[ct]); \
        accB_[ct] = MFMA16(b0, qa0B, accB_[ct]); \
        accB_[ct] = MFMA16(b1, qa1B, accB_[ct]); \
    } }

    // ---- pass 1: row sum of exp2 (no max tracking) ----
    float lA = 0.f, lB = 0.f;

    {
        uint4 k0, k1;
        LOADK(0, k0, k1);
        STOREK(k0, k1);
    }
    for (int kt = 0; kt < nkt; ++kt) {
        __syncthreads();
        f32x4 accA[4] = {}, accB[4] = {};
        QKT2(accA, accB);
        const bool more = kt + 1 < nkt;
        uint4 nk0, nk1;
        if (more) LOADK(kt + 1, nk0, nk1);
        const int dA = q0 + qlA - kt * 64;   // mask iff elem k-offset > dA
        float psA = 0.f, psB = 0.f;
#pragma unroll
        for (int ct = 0; ct < 4; ++ct)
#pragma unroll
            for (int r = 0; r < 4; ++r) {
                const int e = ct * 16 + lg * 4 + r;
                psA += EXP2F(e > dA      ? -1e30f : accA[ct][r]);
                psB += EXP2F(e > dA + 16 ? -1e30f : accB[ct][r]);
            }
        psA += __shfl_xor(psA, 16);
        psA += __shfl_xor(psA, 32);
        psB += __shfl_xor(psB, 16);
        psB += __shfl_xor(psB, 32);
        lA += psA;
        lB += psB;
        __syncthreads();
        if (more) STOREK(nk0, nk1);
    }

    const float lg2ilA = -LOG2F(lA);
    const float lg2ilB = -LOG2F(lB);

    // ---- pass 2: weights + PV ----
    {
        uint4 k0, k1, v0, v1;
        LOADK(0, k0, k1);
        LOADV(0, v0, v1);
        STOREK(k0, k1);
        STOREV(v0, v1);
    }
    f32x4 oA[4] = {}, oB[4] = {};
    const size_t wrowA = ((size_t)bh * SEQ + q0 + qlA) * SEQ;
    const size_t wrowB = wrowA + (size_t)16 * SEQ;

    for (int kt = 0; kt < nkt; ++kt) {
        __syncthreads();
        f32x4 accA[4] = {}, accB[4] = {};
        QKT2(accA, accB);
        const bool more = kt + 1 < nkt;
        uint4 nk0, nk1, nv0, nv1;
        if (more) { LOADK(kt + 1, nk0, nk1); LOADV(kt + 1, nv0, nv1); }
        const int dA = q0 + qlA - kt * 64;
#pragma unroll
        for (int ct = 0; ct < 4; ++ct) {
            f32x4 wA, wB;
            union { bf16 h4[4]; uint2 u; } pkA, pkB;
#pragma unroll
            for (int r = 0; r < 4; ++r) {
                const int e = ct * 16 + lg * 4 + r;
                float a = EXP2F((e > dA      ? -1e30f : accA[ct][r]) + lg2ilA);
                float c = EXP2F((e > dA + 16 ? -1e30f : accB[ct][r]) + lg2ilB);
                wA[r] = a; pkA.h4[r] = __float2bfloat16(a);
                wB[r] = c; pkB.h4[r] = __float2bfloat16(c);
            }
            __builtin_nontemporal_store(
                wA, (f32x4*)&weights[wrowA + kt * 64 + ct * 16 + lg * 4]);
            __builtin_nontemporal_store(
                wB, (f32x4*)&weights[wrowB + kt * 64 + ct * 16 + lg * 4]);
            // packed P transpose into wave-private LDS (A-fragment layout):
            const int sub = ((ct & 1) * 2 + (lg >> 1)) * 16 + l15;
            *(uint2*)&Ps[(((wave * 4 + 0 + (ct >> 1)) * 64) + sub) * 8 + (lg & 1) * 4]
                = pkA.u;
            *(uint2*)&Ps[(((wave * 4 + 2 + (ct >> 1)) * 64) + sub) * 8 + (lg & 1) * 4]
                = pkB.u;
        }
        // PV (swapped: A=V, B=P) -> o[td][r]: d = td*16+lg*4+r, q = l15.
        bf16x8 paA0 = *(const bf16x8*)&Ps[(wave * 4 + 0) * 512 + lane * 8];
        bf16x8 paA1 = *(const bf16x8*)&Ps[(wave * 4 + 1) * 512 + lane * 8];
        bf16x8 paB0 = *(const bf16x8*)&Ps[(wave * 4 + 2) * 512 + lane * 8];
        bf16x8 paB1 = *(const bf16x8*)&Ps[(wave * 4 + 3) * 512 + lane * 8];
#pragma unroll
        for (int td = 0; td < 4; ++td) {
            bf16x8 vb0 = *(const bf16x8*)&Vs[((td * 2 + 0) * 64 + lane) * 8];
            bf16x8 vb1 = *(const bf16x8*)&Vs[((td * 2 + 1) * 64 + lane) * 8];
            oA[td] = MFMA16(vb0, paA0, oA[td]);
            oA[td] = MFMA16(vb1, paA1, oA[td]);
            oB[td] = MFMA16(vb0, paB0, oB[td]);
            oB[td] = MFMA16(vb1, paB1, oB[td]);
        }
        __syncthreads();
        if (more) { STOREK(nk0, nk1); STOREV(nv0, nv1); }
    }

    // O tile write: q = q0+qlA (+16 for B), d = td*16+lg*4+r (packed 8B)
    {
        const size_t obase = ((size_t)b * SEQ + q0 + qlA) * DIM + h * HDIM + lg * 4;
#pragma unroll
        for (int td = 0; td < 4; ++td) {
            union { bf16 h4[4]; uint2 u; } pk;
#pragma unroll
            for (int r = 0; r < 4; ++r) pk.h4[r] = __float2bfloat16(oA[td][r]);
            *(uint2*)&attn_out[obase + td * 16] = pk.u;
        }
#pragma unroll
        for (int td = 0; td < 4; ++td) {
            union { bf16 h4[4]; uint2 u; } pk;
#pragma unroll
            for (int r = 0; r < 4; ++r) pk.h4[r] = __float2bfloat16(oB[td][r]);
            *(uint2*)&attn_out[obase + (size_t)16 * DIM + td * 16] = pk.u;
        }
    }

    // zero-fill masked (upper-triangle) weight columns — full-line NT stores
    const int zc0 = (qt + 1) * QBLK;
    if (zc0 < SEQ) {
        const int nc4 = (SEQ - zc0) >> 2;
        const size_t base = ((size_t)bh * SEQ + q0) * SEQ + zc0;
        const f32x4 z = {0.f, 0.f, 0.f, 0.f};
        for (int r = 0; r < QBLK; ++r)
            for (int c = tid; c < nc4; c += 256)
                __builtin_nontemporal_store(
                    z, (f32x4*)&weights[base + (size_t)r * SEQ + (size_t)c * 4]);
    }
#undef LOADK
#undef STOREK
#undef LOADV
#undef STOREV
#undef QKT2
}

// ---------------------------------------------------------------------------
// Kernel 3: output projection via SWAPPED MFMA core -> packed float4 stores.
// ---------------------------------------------------------------------------
__global__ __launch_bounds__(256) void oproj_mfma_kernel(
    const bf16* __restrict__ A, const bf16* __restrict__ Wo,
    const float* __restrict__ bo, float* __restrict__ out)
{
    __shared__ alignas(16) bf16 smem[16384];
    const int m0 = blockIdx.y * 128, n0 = blockIdx.x * 128;
    f32x4 acc[4][4] = {};
    mfma_core_1024<true>(A, Wo, m0, n0, smem, acc);

    const int tid = threadIdx.x, lane = tid & 63, wave = tid >> 6;
    const int l15 = lane & 15, lg = lane >> 4, wr = wave >> 1, wc = wave & 1;
    f32x4 bv[4];
#pragma unroll
    for (int j = 0; j < 4; ++j)
        bv[j] = *(const f32x4*)&bo[n0 + wc * 64 + j * 16 + lg * 4];
#pragma unroll
    for (int i = 0; i < 4; ++i) {
        int m = m0 + wr * 64 + i * 16 + l15;
#pragma unroll
        for (int j = 0; j < 4; ++j) {
            f32x4 v = acc[i][j] + bv[j];
            *(f32x4*)&out[(size_t)m * DIM + n0 + wc * 64 + j * 16 + lg * 4] = v;
        }
    }
}

// ---------------------------------------------------------------------------
extern "C" void kernel_launch(void* const* d_in, const int* in_sizes, int n_in,
                              void* d_out, int out_size, void* d_ws, size_t ws_size,
                              hipStream_t stream)
{
    const float* Q  = (const float*)d_in[0];
    const float* K  = (const float*)d_in[1];
    const float* V  = (const float*)d_in[2];
    const float* Wq = (const float*)d_in[3];
    const float* Wk = (const float*)d_in[4];
    const float* Wv = (const float*)d_in[5];
    const float* Wo = (const float*)d_in[6];
    const float* bo = (const float*)d_in[7];

    float* out     = (float*)d_out;
    float* weights = out + (size_t)BS * DIM;   // 268,435,456 floats

    // Pre-attn bf16 scratch lives in the TAIL of the weights buffer; its only
    // readers (proj_mfma) complete before attn overwrites all of weights.
    const size_t XN = (size_t)BS * DIM;        // 8,388,608
    const size_t WN = (size_t)DIM * DIM;       // 1,048,576
    const size_t scratch_elems = 3 * XN + 3 * WN;   // bf16 elements
    bf16* cvt = (bf16*)(weights + ((size_t)268435456 - scratch_elems / 2));
    bf16* xq  = cvt;
    bf16* xk  = xq + XN;
    bf16* xv  = xk + XN;
    bf16* wqc = xv + XN;
    bf16* wkc = wqc + WN;
    bf16* wvc = wkc + WN;

    bf16* qws  = (bf16*)d_ws;                  // (B,H,S,D)  bf16 (CS-scaled)
    bf16* kws  = qws + (size_t)BS * DIM;       // (B,H,S,D)  bf16
    bf16* vtws = kws + (size_t)BS * DIM;       // (B,H,D,S)  bf16 (transposed)
    bf16* aws  = vtws + (size_t)BS * DIM;      // (B,S,DIM)  bf16
    bf16* woc  = qws;                          // reuse qws region AFTER attn

    dim3 blk(256);
    cvt_kernel<<<dim3(4096, 6), blk, 0, stream>>>(
        Q, K, V, Wq, Wk, Wv, xq, xk, xv, wqc, wkc, wvc);
    proj_mfma_kernel<<<dim3(DIM / 128, BS / 128, 3), blk, 0, stream>>>(
        xq, xk, xv, wqc, wkc, wvc, qws, kws, vtws);
    attn_kernel<<<dim3(SEQ / QBLK, HEADS, BATCH), blk, 0, stream>>>(
        qws, kws, vtws, weights, aws);
    cvt_wo_kernel<<<dim3(WN / (256 * 8)), blk, 0, stream>>>(Wo, woc);
    oproj_mfma_kernel<<<dim3(DIM / 128, BS / 128), blk, 0, stream>>>(
        aws, woc, bo, out);
}

// Round 14
// 489.393 us; speedup vs baseline: 1.0961x; 1.0961x over previous
//
#include <hip/hip_runtime.h>
#include <hip/hip_bf16.h>

typedef __hip_bfloat16 bf16;
typedef __attribute__((ext_vector_type(8))) short bf16x8;
typedef __attribute__((ext_vector_type(4))) float f32x4;

#define HEADS 16
#define HDIM  64
#define DIM   1024
#define SEQ   2048
#define BATCH 4
#define BS    (BATCH * SEQ)   // 8192
#define CS    0.1803368801111f  // (1/8) * log2(e): folded into Q at proj time

#define EXP2F(x) __builtin_amdgcn_exp2f(x)
#define LOG2F(x) __builtin_amdgcn_logf(x)
#define MFMA16(a, b, c) __builtin_amdgcn_mfma_f32_16x16x32_bf16(a, b, c, 0, 0, 0)

__device__ __forceinline__ void gload_lds16(const void* g, void* l) {
    __builtin_amdgcn_global_load_lds(
        (const __attribute__((address_space(1))) void*)g,
        (__attribute__((address_space(3))) void*)l, 16, 0, 0);
}

__device__ __forceinline__ void cvt8(const float* __restrict__ src, bf16* __restrict__ dst,
                                     size_t i)
{
    float4 f0 = *(const float4*)&src[i];
    float4 f1 = *(const float4*)&src[i + 4];
    union { bf16 h[8]; uint4 u; } pk;
    pk.h[0] = __float2bfloat16(f0.x); pk.h[1] = __float2bfloat16(f0.y);
    pk.h[2] = __float2bfloat16(f0.z); pk.h[3] = __float2bfloat16(f0.w);
    pk.h[4] = __float2bfloat16(f1.x); pk.h[5] = __float2bfloat16(f1.y);
    pk.h[6] = __float2bfloat16(f1.z); pk.h[7] = __float2bfloat16(f1.w);
    *(uint4*)&dst[i] = pk.u;
}

// ---------------------------------------------------------------------------
// Kernel 0a: fp32 -> bf16 for Q,K,V,Wq,Wk,Wv.
// ---------------------------------------------------------------------------
__global__ __launch_bounds__(256) void cvt_kernel(
    const float* __restrict__ Q, const float* __restrict__ K, const float* __restrict__ V,
    const float* __restrict__ Wq, const float* __restrict__ Wk, const float* __restrict__ Wv,
    bf16* __restrict__ xq, bf16* __restrict__ xk, bf16* __restrict__ xv,
    bf16* __restrict__ wq, bf16* __restrict__ wk, bf16* __restrict__ wv)
{
    const int seg = blockIdx.y;
    const float* src; bf16* dst; size_t n;
    switch (seg) {
        case 0: src = Q;  dst = xq; n = (size_t)BS * DIM;   break;
        case 1: src = K;  dst = xk; n = (size_t)BS * DIM;   break;
        case 2: src = V;  dst = xv; n = (size_t)BS * DIM;   break;
        case 3: src = Wq; dst = wq; n = (size_t)DIM * DIM;  break;
        case 4: src = Wk; dst = wk; n = (size_t)DIM * DIM;  break;
        default: src = Wv; dst = wv; n = (size_t)DIM * DIM; break;
    }
    size_t i = ((size_t)blockIdx.x * 256 + threadIdx.x) * 8;
    if (i >= n) return;
    cvt8(src, dst, i);
}

// Kernel 0b: Wo fp32 -> bf16, AFTER attn into the then-dead qws region.
__global__ __launch_bounds__(256) void cvt_wo_kernel(
    const float* __restrict__ Wo, bf16* __restrict__ wo)
{
    size_t i = ((size_t)blockIdx.x * 256 + threadIdx.x) * 8;
    cvt8(Wo, wo, i);
}

// ---------------------------------------------------------------------------
// MFMA GEMM core (fragment-linear LDS, round-2 comment).  SWAP flips the
// C-layout so the register dim indexes B-rows (packed row-major stores).
// ---------------------------------------------------------------------------
template <bool SWAP>
__device__ __forceinline__ void mfma_core_1024(
    const bf16* __restrict__ A, const bf16* __restrict__ B,
    int m0, int n0, bf16* sA, f32x4 acc[4][4])
{
    const int tid = threadIdx.x, lane = tid & 63, wave = tid >> 6;
    const int l15 = lane & 15, lg = lane >> 4;
    const int wr = wave >> 1, wc = wave & 1;
    bf16* sB = sA + 16 * 512;

    const bf16* gsrc = (wave < 2) ? A : B;
    const int   gm0  = (wave < 2) ? m0 : n0;
    bf16*       sdst = (wave < 2) ? sA : sB;
    const int   wv2  = wave & 1;

#define STAGE(k0_) { \
    _Pragma("unroll") for (int u = 0; u < 8; ++u) { \
        const int c = wv2 * 8 + u; \
        const int mg = c >> 1, s = c & 1; \
        gload_lds16(gsrc + (size_t)(gm0 + mg * 16 + l15) * DIM + (k0_) + s * 32 + lg * 8, \
                    sdst + c * 512); \
    } }

    STAGE(0);
#pragma unroll 1
    for (int t = 0; t < DIM / 64; ++t) {
        __syncthreads();
#pragma unroll
        for (int s = 0; s < 2; ++s) {
            bf16x8 af[4], bfr[4];
#pragma unroll
            for (int i = 0; i < 4; ++i)
                af[i] = *(const bf16x8*)(sA + ((wr * 4 + i) * 2 + s) * 512 + lane * 8);
#pragma unroll
            for (int j = 0; j < 4; ++j)
                bfr[j] = *(const bf16x8*)(sB + ((wc * 4 + j) * 2 + s) * 512 + lane * 8);
#pragma unroll
            for (int i = 0; i < 4; ++i)
#pragma unroll
                for (int j = 0; j < 4; ++j) {
                    if (SWAP) acc[i][j] = MFMA16(bfr[j], af[i], acc[i][j]);
                    else      acc[i][j] = MFMA16(af[i], bfr[j], acc[i][j]);
                }
        }
        __syncthreads();
        if (t < DIM / 64 - 1) STAGE((t + 1) * 64);
    }
#undef STAGE
}

// ---------------------------------------------------------------------------
// Kernel 1: QKV projections.  Q out is PRE-SCALED by CS (folds the softmax
// scale+log2e into the GEMM epilogue -> attn needs no per-score multiply).
// ---------------------------------------------------------------------------
__global__ __launch_bounds__(256) void proj_mfma_kernel(
    const bf16* __restrict__ Xq, const bf16* __restrict__ Xk, const bf16* __restrict__ Xv,
    const bf16* __restrict__ Wq, const bf16* __restrict__ Wk, const bf16* __restrict__ Wv,
    bf16* __restrict__ qo, bf16* __restrict__ ko, bf16* __restrict__ vo)
{
    __shared__ alignas(16) bf16 smem[16384];   // 32 KB
    const int z = blockIdx.z;
    const bf16* X = z == 0 ? Xq : z == 1 ? Xk : Xv;
    const bf16* W = z == 0 ? Wq : z == 1 ? Wk : Wv;
    const int m0 = blockIdx.y * 128, n0 = blockIdx.x * 128;

    const int tid = threadIdx.x, lane = tid & 63, wave = tid >> 6;
    const int l15 = lane & 15, lg = lane >> 4, wr = wave >> 1, wc = wave & 1;
    const int h = blockIdx.x * 2 + wc;     // 128-wide n-tile spans 2 heads

    f32x4 acc[4][4] = {};
    if (z != 2) {
        mfma_core_1024<true>(X, W, m0, n0, smem, acc);
        const float osc = (z == 0) ? CS : 1.0f;   // fold softmax scale into Q
        bf16* O = z == 0 ? qo : ko;
#pragma unroll
        for (int i = 0; i < 4; ++i) {
            int m = m0 + wr * 64 + i * 16 + l15;
            int bb = m >> 11, ss = m & (SEQ - 1);
            size_t base = ((size_t)(bb * HEADS + h) * SEQ + ss) * HDIM;
#pragma unroll
            for (int j = 0; j < 4; ++j) {
                union { bf16 h4[4]; uint2 u; } pk;
#pragma unroll
                for (int r = 0; r < 4; ++r) pk.h4[r] = __float2bfloat16(acc[i][j][r] * osc);
                *(uint2*)&O[base + j * 16 + lg * 4] = pk.u;
            }
        }
    } else {
        mfma_core_1024<false>(X, W, m0, n0, smem, acc);
#pragma unroll
        for (int i = 0; i < 4; ++i) {
            int s0 = m0 + wr * 64 + i * 16 + lg * 4;
            int bb = s0 >> 11, ss = s0 & (SEQ - 1);
#pragma unroll
            for (int j = 0; j < 4; ++j) {
                int d = j * 16 + l15;
                union { bf16 h4[4]; uint2 u; } pk;
#pragma unroll
                for (int r = 0; r < 4; ++r) pk.h4[r] = __float2bfloat16(acc[i][j][r]);
                *(uint2*)&vo[((size_t)(bb * HEADS + h) * HDIM + d) * SEQ + ss] = pk.u;
            }
        }
    }
}

// ---------------------------------------------------------------------------
// Kernel 2: causal attention — measured-best configuration (r12, 490 us):
// QBLK=64, 4 waves, swapped QK^T, no-max exp2 softmax (Q pre-scaled by CS),
// normalization folded into exponent, NT weight stores, PV-swap packed O,
// qt-reversed 3D grid.  Seven structural variants on either side of this
// config (8-wave, dbuf, plain stores, XCD-group, QBLK=128/4w) all measured
// neutral-to-worse; this is the plateau point.
// ---------------------------------------------------------------------------
__global__ __launch_bounds__(256) void attn_kernel(
    const bf16* __restrict__ qws, const bf16* __restrict__ kws, const bf16* __restrict__ vtws,
    float* __restrict__ weights, bf16* __restrict__ attn_out)
{
    __shared__ alignas(16) bf16 Ks[4096];
    __shared__ alignas(16) bf16 Vs[4096];
    __shared__ alignas(16) bf16 Ps[4096];

    const int tid  = threadIdx.x;
    const int lane = tid & 63;
    const int wave = tid >> 6;
    const int l15  = lane & 15;
    const int lg   = lane >> 4;
    const int qt = (int)gridDim.x - 1 - (int)blockIdx.x;  // heavy blocks first
    const int h  = blockIdx.y, b = blockIdx.z;
    const int bh = b * HEADS + h;
    const int q0 = qt * 64;
    const int qloc = 16 * wave + l15;      // this lane's q row within tile

    const bf16* qbase = qws + (size_t)bh * SEQ * HDIM;
    const bf16* kbase = kws + (size_t)bh * SEQ * HDIM;
    const bf16* vbase = vtws + (size_t)bh * HDIM * SEQ;

    bf16x8 qa0, qa1;
    {
        const bf16* qp = qbase + (size_t)(q0 + qloc) * HDIM + lg * 8;
        qa0 = *(const bf16x8*)qp;
        qa1 = *(const bf16x8*)(qp + 32);
    }

#define LOADK(kt_, r0, r1) { \
    const bf16* rp = kbase + (size_t)((kt_) * 64 + 16 * wave + l15) * HDIM + lg * 8; \
    r0 = *(const uint4*)rp; r1 = *(const uint4*)(rp + 32); }
#define STOREK(r0, r1) { \
    *(uint4*)&Ks[((wave * 2 + 0) * 64 + lane) * 8] = r0; \
    *(uint4*)&Ks[((wave * 2 + 1) * 64 + lane) * 8] = r1; }
#define LOADV(kt_, r0, r1) { \
    const bf16* rp = vbase + (size_t)(16 * wave + l15) * SEQ + (kt_) * 64 + lg * 8; \
    r0 = *(const uint4*)rp; r1 = *(const uint4*)(rp + 32); }
#define STOREV(r0, r1) { \
    *(uint4*)&Vs[((wave * 2 + 0) * 64 + lane) * 8] = r0; \
    *(uint4*)&Vs[((wave * 2 + 1) * 64 + lane) * 8] = r1; }
// swapped: A = K chunk, B = Q  ->  acc[ct][r] = s*CS for q=l15, k=ct*16+lg*4+r
#define QKT(acc_) { \
    _Pragma("unroll") \
    for (int ct = 0; ct < 4; ++ct) { \
        bf16x8 b0 = *(const bf16x8*)&Ks[((ct * 2 + 0) * 64 + lane) * 8]; \
        bf16x8 b1 = *(const bf16x8*)&Ks[((ct * 2 + 1) * 64 + lane) * 8]; \
        acc_[ct] = MFMA16(b0, qa0, acc_[ct]); \
        acc_[ct] = MFMA16(b1, qa1, acc_[ct]); \
    } }

    // ---- pass 1: row sum of exp2 (no max tracking needed) ----
    float l_run = 0.f;

    {
        uint4 k0, k1;
        LOADK(0, k0, k1);
        STOREK(k0, k1);
    }
    for (int kt = 0; kt <= qt; ++kt) {
        __syncthreads();
        f32x4 acc[4] = {};
        QKT(acc);
        const bool more = kt < qt;
        uint4 nk0, nk1;
        if (more) LOADK(kt + 1, nk0, nk1);
        const bool diag = (kt == qt);
        float ps = 0.f;
#pragma unroll
        for (int ct = 0; ct < 4; ++ct)
#pragma unroll
            for (int r = 0; r < 4; ++r) {
                float v = acc[ct][r];
                if (diag && (ct * 16 + lg * 4 + r > qloc)) v = -1e30f;
                ps += EXP2F(v);
            }
        ps += __shfl_xor(ps, 16);
        ps += __shfl_xor(ps, 32);
        l_run += ps;
        __syncthreads();
        if (more) STOREK(nk0, nk1);
    }

    const float lg2il = -LOG2F(l_run);   // fold normalization into exponent

    // ---- pass 2: weights + PV ----
    {
        uint4 k0, k1, v0, v1;
        LOADK(0, k0, k1);
        LOADV(0, v0, v1);
        STOREK(k0, k1);
        STOREV(v0, v1);
    }
    f32x4 oacc[4] = {};
    const size_t wrow = ((size_t)bh * SEQ + q0 + qloc) * SEQ;

    for (int kt = 0; kt <= qt; ++kt) {
        __syncthreads();
        f32x4 acc[4] = {};
        QKT(acc);
        const bool more = kt < qt;
        uint4 nk0, nk1, nv0, nv1;
        if (more) { LOADK(kt + 1, nk0, nk1); LOADV(kt + 1, nv0, nv1); }
        const bool diag = (kt == qt);
#pragma unroll
        for (int ct = 0; ct < 4; ++ct) {
            f32x4 w4;
            union { bf16 h4[4]; uint2 u; } pk;
#pragma unroll
            for (int r = 0; r < 4; ++r) {
                float v = acc[ct][r];
                if (diag && (ct * 16 + lg * 4 + r > qloc)) v = -1e30f;
                float w = EXP2F(v + lg2il);
                w4[r] = w;
                pk.h4[r] = __float2bfloat16(w);
            }
            // NT store (measured: plain cached stores cost +70us total)
            __builtin_nontemporal_store(
                w4, (f32x4*)&weights[wrow + kt * 64 + ct * 16 + lg * 4]);
            // packed P transpose into wave-private LDS (A-fragment layout):
            *(uint2*)&Ps[(((wave * 2 + (ct >> 1)) * 64
                           + ((ct & 1) * 2 + (lg >> 1)) * 16 + l15) * 8
                          + (lg & 1) * 4)] = pk.u;
        }
        // PV (SWAPPED: A=V, B=P) -> oacc[td][r]: d = td*16+lg*4+r, q = l15.
        bf16x8 pa0 = *(const bf16x8*)&Ps[((wave * 2 + 0) * 64 + lane) * 8];
        bf16x8 pa1 = *(const bf16x8*)&Ps[((wave * 2 + 1) * 64 + lane) * 8];
#pragma unroll
        for (int td = 0; td < 4; ++td) {
            bf16x8 vb0 = *(const bf16x8*)&Vs[((td * 2 + 0) * 64 + lane) * 8];
            bf16x8 vb1 = *(const bf16x8*)&Vs[((td * 2 + 1) * 64 + lane) * 8];
            oacc[td] = MFMA16(vb0, pa0, oacc[td]);
            oacc[td] = MFMA16(vb1, pa1, oacc[td]);
        }
        __syncthreads();
        if (more) { STOREK(nk0, nk1); STOREV(nv0, nv1); }
    }

    // O tile write: q = q0+16*wave+l15 (lane), d = td*16+lg*4+r (packed 8B)
    {
        const size_t obase = ((size_t)b * SEQ + q0 + 16 * wave + l15) * DIM
                           + h * HDIM + lg * 4;
#pragma unroll
        for (int td = 0; td < 4; ++td) {
            union { bf16 h4[4]; uint2 u; } pk;
#pragma unroll
            for (int r = 0; r < 4; ++r) pk.h4[r] = __float2bfloat16(oacc[td][r]);
            *(uint2*)&attn_out[obase + td * 16] = pk.u;
        }
    }

    // zero-fill masked (upper-triangle) weight columns — full-line NT stores
    const int zc0 = (qt + 1) * 64;
    if (zc0 < SEQ) {
        const int nc4 = (SEQ - zc0) >> 2;
        const size_t base = ((size_t)bh * SEQ + q0) * SEQ + zc0;
        const f32x4 z = {0.f, 0.f, 0.f, 0.f};
        for (int r = 0; r < 64; ++r)
            for (int c = tid; c < nc4; c += 256)
                __builtin_nontemporal_store(
                    z, (f32x4*)&weights[base + (size_t)r * SEQ + (size_t)c * 4]);
    }
#undef LOADK
#undef STOREK
#undef LOADV
#undef STOREV
#undef QKT
}

// ---------------------------------------------------------------------------
// Kernel 3: output projection via SWAPPED MFMA core -> packed float4 stores.
// ---------------------------------------------------------------------------
__global__ __launch_bounds__(256) void oproj_mfma_kernel(
    const bf16* __restrict__ A, const bf16* __restrict__ Wo,
    const float* __restrict__ bo, float* __restrict__ out)
{
    __shared__ alignas(16) bf16 smem[16384];
    const int m0 = blockIdx.y * 128, n0 = blockIdx.x * 128;
    f32x4 acc[4][4] = {};
    mfma_core_1024<true>(A, Wo, m0, n0, smem, acc);

    const int tid = threadIdx.x, lane = tid & 63, wave = tid >> 6;
    const int l15 = lane & 15, lg = lane >> 4, wr = wave >> 1, wc = wave & 1;
    f32x4 bv[4];
#pragma unroll
    for (int j = 0; j < 4; ++j)
        bv[j] = *(const f32x4*)&bo[n0 + wc * 64 + j * 16 + lg * 4];
#pragma unroll
    for (int i = 0; i < 4; ++i) {
        int m = m0 + wr * 64 + i * 16 + l15;
#pragma unroll
        for (int j = 0; j < 4; ++j) {
            f32x4 v = acc[i][j] + bv[j];
            *(f32x4*)&out[(size_t)m * DIM + n0 + wc * 64 + j * 16 + lg * 4] = v;
        }
    }
}

// ---------------------------------------------------------------------------
extern "C" void kernel_launch(void* const* d_in, const int* in_sizes, int n_in,
                              void* d_out, int out_size, void* d_ws, size_t ws_size,
                              hipStream_t stream)
{
    const float* Q  = (const float*)d_in[0];
    const float* K  = (const float*)d_in[1];
    const float* V  = (const float*)d_in[2];
    const float* Wq = (const float*)d_in[3];
    const float* Wk = (const float*)d_in[4];
    const float* Wv = (const float*)d_in[5];
    const float* Wo = (const float*)d_in[6];
    const float* bo = (const float*)d_in[7];

    float* out     = (float*)d_out;
    float* weights = out + (size_t)BS * DIM;   // 268,435,456 floats

    // Pre-attn bf16 scratch lives in the TAIL of the weights buffer; its only
    // readers (proj_mfma) complete before attn overwrites all of weights.
    const size_t XN = (size_t)BS * DIM;        // 8,388,608
    const size_t WN = (size_t)DIM * DIM;       // 1,048,576
    const size_t scratch_elems = 3 * XN + 3 * WN;   // bf16 elements
    bf16* cvt = (bf16*)(weights + ((size_t)268435456 - scratch_elems / 2));
    bf16* xq  = cvt;
    bf16* xk  = xq + XN;
    bf16* xv  = xk + XN;
    bf16* wqc = xv + XN;
    bf16* wkc = wqc + WN;
    bf16* wvc = wkc + WN;

    bf16* qws  = (bf16*)d_ws;                  // (B,H,S,D)  bf16 (CS-scaled)
    bf16* kws  = qws + (size_t)BS * DIM;       // (B,H,S,D)  bf16
    bf16* vtws = kws + (size_t)BS * DIM;       // (B,H,D,S)  bf16 (transposed)
    bf16* aws  = vtws + (size_t)BS * DIM;      // (B,S,DIM)  bf16
    bf16* woc  = qws;                          // reuse qws region AFTER attn

    dim3 blk(256);
    cvt_kernel<<<dim3(4096, 6), blk, 0, stream>>>(
        Q, K, V, Wq, Wk, Wv, xq, xk, xv, wqc, wkc, wvc);
    proj_mfma_kernel<<<dim3(DIM / 128, BS / 128, 3), blk, 0, stream>>>(
        xq, xk, xv, wqc, wkc, wvc, qws, kws, vtws);
    attn_kernel<<<dim3(SEQ / 64, HEADS, BATCH), blk, 0, stream>>>(
        qws, kws, vtws, weights, aws);
    cvt_wo_kernel<<<dim3(WN / (256 * 8)), blk, 0, stream>>>(Wo, woc);
    oproj_mfma_kernel<<<dim3(DIM / 128, BS / 128), blk, 0, stream>>>(
        aws, woc, bo, out);
}